// Round 2
// baseline (37115.991 us; speedup 1.0000x reference)
//
#include <hip/hip_runtime.h>

// ---------------------------------------------------------------------------
// Bidirectional 2-layer tanh RNN (B=32, T=2048, V=8192, H=512, O=1024)
//   L0 pre = gather(Wih0^T, x) + b            (table transposed on device)
//   h_t = tanh(pre_t + h_{t-1} @ Whh^T)       (serial scan, 4 sequences)
//   L1 pre = h0cat @ Wih1^T + b               (GEMM, M=65536 N=1024 K=1024)
//   out = h1cat @ fcW^T + fcb                 (GEMM, M=65536 N=1024 K=1024)
// Precision: weights & h split into bf16 hi+lo; 3-product MFMA (hh+hl+lh)
// gives ~2^-16 relative error per matmul (fp32-like through the recurrence).
// ---------------------------------------------------------------------------

typedef unsigned short u16;
typedef unsigned int   u32;
typedef __attribute__((ext_vector_type(8))) short bf16x8;   // 8 bf16 = 4 VGPR
typedef __attribute__((ext_vector_type(4))) float f32x4;

#define B_  32
#define T_  2048
#define V_  8192
#define H_  512
#define HC_ 1024

__device__ __forceinline__ u16 f2bf(float f) {           // fp32 -> bf16 RNE
  u32 u = __float_as_uint(f);
  u32 r = (u + 0x7fffu + ((u >> 16) & 1u)) >> 16;
  return (u16)r;
}
__device__ __forceinline__ float bf2f(u16 b) { return __uint_as_float(((u32)b) << 16); }

__device__ __forceinline__ float tanh_fast(float x) {    // 1 - 2/(e^{2|x|}+1), sign-restored
  float a = fabsf(x);
  float e = __expf(2.f * a);
  float r = 1.f - 2.f / (e + 1.f);
  return copysignf(r, x);
}

__device__ __forceinline__ f32x4 mfma16(bf16x8 a, bf16x8 b, f32x4 c) {
  return __builtin_amdgcn_mfma_f32_16x16x32_bf16(a, b, c, 0, 0, 0);
}

// ---------------------------------------------------------------------------
// Prep: transpose Wih0 [2][H][V] -> WT0 [2][V][H]  (gather becomes row-read)
// ---------------------------------------------------------------------------
__global__ void transpose_wih0(const float* __restrict__ src, float* __restrict__ dst) {
  __shared__ float tile[32][33];
  int d  = blockIdx.z;
  int v0 = blockIdx.x * 32, h0 = blockIdx.y * 32;
  int tx = threadIdx.x, ty = threadIdx.y;          // 32 x 8
#pragma unroll
  for (int i = 0; i < 4; i++)
    tile[ty + 8 * i][tx] = src[((size_t)d * H_ + h0 + ty + 8 * i) * V_ + v0 + tx];
  __syncthreads();
#pragma unroll
  for (int i = 0; i < 4; i++)
    dst[((size_t)d * V_ + v0 + ty + 8 * i) * H_ + h0 + tx] = tile[tx][ty + 8 * i];
}

// ---------------------------------------------------------------------------
// Prep: split fp32 -> bf16 hi + bf16 lo planes
// ---------------------------------------------------------------------------
__global__ void split_hilo(const float* __restrict__ src, u16* __restrict__ hi,
                           u16* __restrict__ lo, int n) {
  int i = blockIdx.x * 256 + threadIdx.x;
  if (i < n) {
    float v = src[i];
    u16 h = f2bf(v);
    hi[i] = h;
    lo[i] = f2bf(v - bf2f(h));
  }
}

// ---------------------------------------------------------------------------
// Recurrent scan. Grid of 64 blocks; block w: c=w&7 (exit if >=4), s=w>>3.
//   c encodes (dir d = c>>1, batch-group g = c&1); s = j-slice (64 cols).
//   => sync group = 8 blocks with equal c => same XCD under %8 round-robin
//      (perf heuristic only; protocol is agent-scope-correct regardless).
// Each block: Whh[j-slice] hi/lo persistent in VGPRs (128/lane);
//   h (16 batches x 512, hi/lo bf16) staged in LDS with XOR swizzle.
// Per step: 192 MFMA -> tanh -> write hi/lo h-planes (they double as the
//   exchange buffer; one writer per address => no double-buffer needed)
//   -> fence -> flag (agent release) -> poll count==8 (acquire) -> restage
//   32KB from L3.
// ---------------------------------------------------------------------------
__global__ __launch_bounds__(256, 1) void rnn_scan(
    const u16* __restrict__ WhhHi, const u16* __restrict__ WhhLo,   // [2][512][512]
    const float* __restrict__ WT0,                                  // [2][V][512] (layer0)
    const int* __restrict__ xIdx,                                   // [B][T]     (layer0)
    const float* __restrict__ bih, const float* __restrict__ bhh,   // [2][512]   (layer0)
    const float* __restrict__ preBuf,                               // [2][B][T][512] (layer1)
    u16* __restrict__ hHiOut, u16* __restrict__ hLoOut,             // [B][T][1024]
    int* __restrict__ flags, int layer) {
  int w = blockIdx.x;
  int c = w & 7;
  if (c >= 4) return;
  int s = w >> 3;                  // 0..7  j-slice
  int d = c >> 1, g = c & 1;
  int tid = threadIdx.x;
  int wv = tid >> 6, l = tid & 63;
  int lr = l & 15, lq = l >> 4;
  int jglob = s * 64 + wv * 16 + lr;   // this lane's output column (B-frag col, D col)
  int b0 = g * 16;

  __shared__ __align__(16) unsigned char hHiS[16 * 1024];  // [16 rows][512 bf16], swizzled
  __shared__ __align__(16) unsigned char hLoS[16 * 1024];

  // h_{-1} = 0
  {
    f32x4 z = {0.f, 0.f, 0.f, 0.f};
    for (int i = tid; i < 1024; i += 256) {
      *(f32x4*)(hHiS + i * 16) = z;
      *(f32x4*)(hLoS + i * 16) = z;
    }
  }

  // persistent weight fragments: B[k][n] = Whh[n][k]; lane: n=l&15, k=kk*32+lq*8+e
  bf16x8 Bhi[16], Blo[16];
  {
    const u16* baseH = WhhHi + ((size_t)d * H_ + jglob) * H_ + lq * 8;
    const u16* baseL = WhhLo + ((size_t)d * H_ + jglob) * H_ + lq * 8;
#pragma unroll
    for (int kk = 0; kk < 16; kk++) {
      Bhi[kk] = *(const bf16x8*)(baseH + kk * 32);
      Blo[kk] = *(const bf16x8*)(baseL + kk * 32);
    }
  }
  float bias = 0.f;
  if (layer == 0) bias = bih[d * H_ + jglob] + bhh[d * H_ + jglob];

  int* flagp = flags + ((layer * 2 + d) * 2 + g) * T_;

  __syncthreads();

  auto loadPre = [&](int tau, float* dst) {
#pragma unroll
    for (int r = 0; r < 4; r++) {
      int b = b0 + lq * 4 + r;
      if (layer == 0) {
        int xv = xIdx[b * T_ + tau];
        dst[r] = WT0[((size_t)d * V_ + xv) * H_ + jglob];
      } else {
        dst[r] = preBuf[(((size_t)d * B_ + b) * T_ + tau) * H_ + jglob];
      }
    }
  };

  float preC[4];
  loadPre((d == 0) ? 0 : T_ - 1, preC);

  for (int t = 0; t < T_; t++) {
    int tau = (d == 0) ? t : (T_ - 1 - t);

    float preN[4];
    if (t < T_ - 1) {                      // prefetch next step's pre (hides gather latency)
      int tauN = (d == 0) ? (t + 1) : (T_ - 2 - t);
      loadPre(tauN, preN);
    }

    // acc = h_prev @ Whh_slice^T  via 3 split products (hh + hl + lh)
    f32x4 acc0 = {0.f, 0.f, 0.f, 0.f}, acc1 = acc0, acc2 = acc0;
#pragma unroll
    for (int kk = 0; kk < 16; kk++) {
      int bo = kk * 64 + lq * 16;
      int sw = bo ^ ((lr & 7) << 4);       // XOR swizzle: rows spread across 16B slots
      bf16x8 ah = *(const bf16x8*)(hHiS + lr * 1024 + sw);
      bf16x8 al = *(const bf16x8*)(hLoS + lr * 1024 + sw);
      acc0 = mfma16(ah, Bhi[kk], acc0);
      acc1 = mfma16(ah, Blo[kk], acc1);
      acc2 = mfma16(al, Bhi[kk], acc2);
    }

    // epilogue: tanh, split, publish.  D layout: col=l&15 (j), row=lq*4+r (batch)
#pragma unroll
    for (int r = 0; r < 4; r++) {
      float v = acc0[r] + acc1[r] + acc2[r] + preC[r] + bias;
      v = tanh_fast(v);
      u16 hv = f2bf(v);
      u16 lv = f2bf(v - bf2f(hv));
      size_t addr = (((size_t)(b0 + lq * 4 + r)) * T_ + tau) * HC_ + d * H_ + jglob;
      hHiOut[addr] = hv;
      hLoOut[addr] = lv;
    }

    if (t < T_ - 1) {
      __threadfence();                     // make h stores agent-visible
      __syncthreads();                     // every thread fenced
      if (tid == 0) {
        __hip_atomic_fetch_add(flagp + t, 1, __ATOMIC_RELEASE, __HIP_MEMORY_SCOPE_AGENT);
        while (__hip_atomic_load(flagp + t, __ATOMIC_RELAXED, __HIP_MEMORY_SCOPE_AGENT) < 8)
          __builtin_amdgcn_s_sleep(2);
        (void)__hip_atomic_load(flagp + t, __ATOMIC_ACQUIRE, __HIP_MEMORY_SCOPE_AGENT);
      }
      __syncthreads();
      // restage full h(tau) for our 16 batches into LDS (coalesced 1KB/wave rows)
#pragma unroll
      for (int it = 0; it < 4; it++) {
        int ci = it * 256 + tid;
        int row = ci >> 6;                 // batch-in-group
        int cg = ci & 63;                  // 16B chunk within row
        size_t ga = (((size_t)(b0 + row)) * T_ + tau) * HC_ + d * H_ + cg * 8;
        u32 dsb = row * 1024 + ((cg ^ (row & 7)) << 4);
        *(f32x4*)(hHiS + dsb) = *(const f32x4*)(hHiOut + ga);
        *(f32x4*)(hLoS + dsb) = *(const f32x4*)(hLoOut + ga);
      }
      __syncthreads();
#pragma unroll
      for (int r = 0; r < 4; r++) preC[r] = preN[r];
    }
  }
}

// ---------------------------------------------------------------------------
// GEMM  C[M=65536][N=1024] = A[M][K] * B[N][K]^T (+bias1[n] +bias2[n])
// A,B given as bf16 hi/lo planes; 3 split products. 128x128 tile, BK=64,
// 4 waves in 2x2 of 64x64, reg-staged LDS with XOR swizzle.
// outMode 0: C[row*1024+n]   (FC -> d_out)
// outMode 1: C[(n>>9)*M*512 + row*512 + (n&511)]   (pre1 [2][M][512])
// ---------------------------------------------------------------------------
__global__ __launch_bounds__(256, 2) void gemm_split3(
    const u16* __restrict__ Ahi, const u16* __restrict__ Alo,
    const u16* __restrict__ Bhi, const u16* __restrict__ Blo,
    float* __restrict__ Cout,
    const float* __restrict__ bias1, const float* __restrict__ bias2,
    int Kdim, int outMode) {
  __shared__ __align__(16) u16 AsH[128 * 64], AsL[128 * 64];
  __shared__ __align__(16) u16 BsH[128 * 64], BsL[128 * 64];
  int tid = threadIdx.x;
  int wv = tid >> 6, l = tid & 63, lr = l & 15, lq = l >> 4;
  int wr = wv >> 1, wc = wv & 1;
  size_t row0 = (size_t)blockIdx.y * 128;
  int col0 = blockIdx.x * 128;

  f32x4 zero = {0.f, 0.f, 0.f, 0.f};
  f32x4 acc[4][4];
#pragma unroll
  for (int i = 0; i < 4; i++)
#pragma unroll
    for (int j = 0; j < 4; j++) acc[i][j] = zero;

  int nk = Kdim >> 6;
  for (int ks = 0; ks < nk; ks++) {
    __syncthreads();
#pragma unroll
    for (int it = 0; it < 4; it++) {       // stage 4 x 16KB, swizzled dest
      int ci = it * 256 + tid;
      int row = ci >> 3;
      int cg = ci & 7;
      u32 dsb = row * 128 + ((cg ^ (row & 7)) << 4);
      size_t ga = (row0 + row) * (size_t)Kdim + ks * 64 + cg * 8;
      size_t gb = ((size_t)(col0 + row)) * (size_t)Kdim + ks * 64 + cg * 8;
      *(f32x4*)((char*)AsH + dsb) = *(const f32x4*)(Ahi + ga);
      *(f32x4*)((char*)AsL + dsb) = *(const f32x4*)(Alo + ga);
      *(f32x4*)((char*)BsH + dsb) = *(const f32x4*)(Bhi + gb);
      *(f32x4*)((char*)BsL + dsb) = *(const f32x4*)(Blo + gb);
    }
    __syncthreads();
#pragma unroll
    for (int kk = 0; kk < 2; kk++) {
      bf16x8 aH[4], aL[4], bH[4], bL[4];
#pragma unroll
      for (int mt = 0; mt < 4; mt++) {
        int row = wr * 64 + mt * 16 + lr;
        u32 off = row * 128 + (((kk * 4 + lq) ^ (row & 7)) << 4);
        aH[mt] = *(const bf16x8*)((const char*)AsH + off);
        aL[mt] = *(const bf16x8*)((const char*)AsL + off);
      }
#pragma unroll
      for (int nt = 0; nt < 4; nt++) {
        int row = wc * 64 + nt * 16 + lr;
        u32 off = row * 128 + (((kk * 4 + lq) ^ (row & 7)) << 4);
        bH[nt] = *(const bf16x8*)((const char*)BsH + off);
        bL[nt] = *(const bf16x8*)((const char*)BsL + off);
      }
#pragma unroll
      for (int mt = 0; mt < 4; mt++)
#pragma unroll
        for (int nt = 0; nt < 4; nt++) {
          acc[mt][nt] = mfma16(aH[mt], bH[nt], acc[mt][nt]);
          acc[mt][nt] = mfma16(aH[mt], bL[nt], acc[mt][nt]);
          acc[mt][nt] = mfma16(aL[mt], bH[nt], acc[mt][nt]);
        }
    }
  }
#pragma unroll
  for (int mt = 0; mt < 4; mt++)
#pragma unroll
    for (int nt = 0; nt < 4; nt++)
#pragma unroll
      for (int r = 0; r < 4; r++) {
        size_t row = row0 + wr * 64 + mt * 16 + lq * 4 + r;
        int n = col0 + wc * 64 + nt * 16 + lr;
        float v = acc[mt][nt][r];
        if (bias1) v += bias1[n];
        if (bias2) v += bias2[n];
        size_t oaddr = outMode ? ((size_t)(n >> 9) * ((size_t)65536 * 512) + row * 512 + (n & 511))
                               : (row * 1024 + n);
        Cout[oaddr] = v;
      }
}

// ---------------------------------------------------------------------------
extern "C" void kernel_launch(void* const* d_in, const int* in_sizes, int n_in,
                              void* d_out, int out_size, void* d_ws, size_t ws_size,
                              hipStream_t stream) {
  (void)in_sizes; (void)n_in; (void)out_size; (void)ws_size;
  const int*   x    = (const int*)d_in[0];
  const float* Wih0 = (const float*)d_in[1];
  const float* Whh0 = (const float*)d_in[2];
  const float* bih0 = (const float*)d_in[3];
  const float* bhh0 = (const float*)d_in[4];
  const float* Wih1 = (const float*)d_in[5];
  const float* Whh1 = (const float*)d_in[6];
  const float* bih1 = (const float*)d_in[7];
  const float* bhh1 = (const float*)d_in[8];
  const float* fcW  = (const float*)d_in[9];
  const float* fcb  = (const float*)d_in[10];
  float* out = (float*)d_out;

  // workspace layout (all 16B-aligned): ~556 MB
  char* w = (char*)d_ws;
  float* WT0   = (float*)w;  w += (size_t)2 * V_ * H_ * 4;        // 32 MB
  u16* Whh0Hi  = (u16*)w;    w += (size_t)2 * H_ * H_ * 2;        // 1 MB
  u16* Whh0Lo  = (u16*)w;    w += (size_t)2 * H_ * H_ * 2;
  u16* Whh1Hi  = (u16*)w;    w += (size_t)2 * H_ * H_ * 2;
  u16* Whh1Lo  = (u16*)w;    w += (size_t)2 * H_ * H_ * 2;
  u16* Wih1Hi  = (u16*)w;    w += (size_t)HC_ * HC_ * 2;          // 2 MB
  u16* Wih1Lo  = (u16*)w;    w += (size_t)HC_ * HC_ * 2;
  u16* fcWHi   = (u16*)w;    w += (size_t)HC_ * HC_ * 2;
  u16* fcWLo   = (u16*)w;    w += (size_t)HC_ * HC_ * 2;
  int* flags   = (int*)w;    w += (size_t)2 * 2 * 2 * T_ * 4;     // 64 KB
  u16* hHi     = (u16*)w;    w += (size_t)B_ * T_ * HC_ * 2;      // 128 MB (h0, reused as h1)
  u16* hLo     = (u16*)w;    w += (size_t)B_ * T_ * HC_ * 2;      // 128 MB
  float* pre1  = (float*)w;  w += (size_t)2 * B_ * T_ * H_ * 4;   // 256 MB

  hipMemsetAsync(flags, 0, (size_t)2 * 2 * 2 * T_ * 4, stream);

  transpose_wih0<<<dim3(V_ / 32, H_ / 32, 2), dim3(32, 8), 0, stream>>>(Wih0, WT0);
  split_hilo<<<(2 * H_ * H_) / 256, 256, 0, stream>>>(Whh0, Whh0Hi, Whh0Lo, 2 * H_ * H_);
  split_hilo<<<(2 * H_ * H_) / 256, 256, 0, stream>>>(Whh1, Whh1Hi, Whh1Lo, 2 * H_ * H_);
  split_hilo<<<(HC_ * HC_) / 256, 256, 0, stream>>>(Wih1, Wih1Hi, Wih1Lo, HC_ * HC_);
  split_hilo<<<(HC_ * HC_) / 256, 256, 0, stream>>>(fcW, fcWHi, fcWLo, HC_ * HC_);

  // layer 0 scan (writes hHi/hLo)
  rnn_scan<<<64, 256, 0, stream>>>(Whh0Hi, Whh0Lo, WT0, x, bih0, bhh0, nullptr,
                                   hHi, hLo, flags, 0);
  // layer 1 pre = h0cat @ Wih1^T + bih1 + bhh1  -> pre1 [2][B*T][512]
  gemm_split3<<<dim3(8, 512), 256, 0, stream>>>(hHi, hLo, Wih1Hi, Wih1Lo, pre1,
                                                bih1, bhh1, HC_, 1);
  // layer 1 scan (reads pre1, overwrites hHi/hLo with h1)
  rnn_scan<<<64, 256, 0, stream>>>(Whh1Hi, Whh1Lo, nullptr, nullptr, nullptr, nullptr,
                                   pre1, hHi, hLo, flags, 1);
  // FC: out = h1cat @ fcW^T + fcb
  gemm_split3<<<dim3(8, 512), 256, 0, stream>>>(hHi, hLo, fcWHi, fcWLo, out,
                                                fcb, nullptr, HC_, 0);
}

// Round 3
// 28433.536 us; speedup vs baseline: 1.3054x; 1.3054x over previous
//
#include <hip/hip_runtime.h>

// ---------------------------------------------------------------------------
// Bidirectional 2-layer tanh RNN (B=32, T=2048, V=8192, H=512, O=1024)
// v3: scan redesigned after first profile (9.2us/step, MfmaUtil 0.4%):
//   - h exchange via MALL (relaxed agent atomics, L2-bypass) -- NO
//     threadfence / release / acquire => no buffer_wbl2 / buffer_inv per step.
//   - Whh hi/lo resident in LDS (128KB, swizzled), B-fragments pinned in
//     VGPRs via asm (v2 had VGPR_Count=124 < the 128 needed => reload storm).
//   - h staging LDS 32KB; total LDS 160KB, 1 block/CU, 32 active blocks.
// Precision unchanged (passed, absmax 2^-10): bf16 hi/lo split, 3 products.
// ---------------------------------------------------------------------------

typedef unsigned short u16;
typedef unsigned int   u32;
typedef __attribute__((ext_vector_type(8))) short bf16x8;   // 8 bf16 = 4 VGPR
typedef __attribute__((ext_vector_type(4))) float f32x4;
typedef __attribute__((ext_vector_type(4))) unsigned int u32x4;

#define B_  32
#define T_  2048
#define V_  8192
#define H_  512
#define HC_ 1024

__device__ __forceinline__ u16 f2bf(float f) {           // fp32 -> bf16 RNE
  u32 u = __float_as_uint(f);
  u32 r = (u + 0x7fffu + ((u >> 16) & 1u)) >> 16;
  return (u16)r;
}
__device__ __forceinline__ float bf2f(u16 b) { return __uint_as_float(((u32)b) << 16); }

__device__ __forceinline__ float tanh_fast(float x) {    // 1 - 2/(e^{2|x|}+1)
  float a = fabsf(x);
  float e = __expf(2.f * a);
  float r = 1.f - 2.f / (e + 1.f);
  return copysignf(r, x);
}

__device__ __forceinline__ f32x4 mfma16(bf16x8 a, bf16x8 b, f32x4 c) {
  return __builtin_amdgcn_mfma_f32_16x16x32_bf16(a, b, c, 0, 0, 0);
}

// ---------------------------------------------------------------------------
// Prep: transpose Wih0 [2][H][V] -> WT0 [2][V][H]  (gather becomes row-read)
// ---------------------------------------------------------------------------
__global__ void transpose_wih0(const float* __restrict__ src, float* __restrict__ dst) {
  __shared__ float tile[32][33];
  int d  = blockIdx.z;
  int v0 = blockIdx.x * 32, h0 = blockIdx.y * 32;
  int tx = threadIdx.x, ty = threadIdx.y;          // 32 x 8
#pragma unroll
  for (int i = 0; i < 4; i++)
    tile[ty + 8 * i][tx] = src[((size_t)d * H_ + h0 + ty + 8 * i) * V_ + v0 + tx];
  __syncthreads();
#pragma unroll
  for (int i = 0; i < 4; i++)
    dst[((size_t)d * V_ + v0 + ty + 8 * i) * H_ + h0 + tx] = tile[tx][ty + 8 * i];
}

// ---------------------------------------------------------------------------
// Prep: split fp32 -> bf16 hi + bf16 lo planes (GEMM operands only now)
// ---------------------------------------------------------------------------
__global__ void split_hilo(const float* __restrict__ src, u16* __restrict__ hi,
                           u16* __restrict__ lo, int n) {
  int i = blockIdx.x * 256 + threadIdx.x;
  if (i < n) {
    float v = src[i];
    u16 h = f2bf(v);
    hi[i] = h;
    lo[i] = f2bf(v - bf2f(h));
  }
}

// ---------------------------------------------------------------------------
// Recurrent scan. Grid 64; block w: c=w&7 (exit if >=4), s=w>>3 (j-slice).
//   c = (dir d = c>>1, batch-group g = c&1); 8 blocks per (d,g) sync group,
//   co-located on one XCD under %8 round-robin (perf heuristic only).
// LDS: Whh j-slice hi/lo 128KB (swizzled) + h staging 32KB = 160KB.
// Exchange: packed (hi<<16|lo) u32 per h element, double-buffered by t-parity,
//   relaxed agent atomics (sc0 sc1 -> MALL-coherent, no cache maintenance).
// Flags: relaxed fetch_add + relaxed poll; __syncthreads' vmcnt(0) drain
//   orders the sc1 data stores before the flag (MALL = single coherence pt).
// ---------------------------------------------------------------------------
__global__ __launch_bounds__(256, 1) void rnn_scan(
    const float* __restrict__ Whh,                                  // [2][512][512] fp32
    const float* __restrict__ WT0,                                  // [2][V][512] (layer0)
    const int* __restrict__ xIdx,                                   // [B][T]     (layer0)
    const float* __restrict__ bih, const float* __restrict__ bhh,   // [2][512]   (layer0)
    const float* __restrict__ preBuf,                               // [2][B][T][512] (layer1)
    u16* __restrict__ hHiOut, u16* __restrict__ hLoOut,             // [B][T][1024]
    u32* __restrict__ hx,                                           // [4][2][16][512]
    int* __restrict__ flags, int layer) {
  int w = blockIdx.x;
  int c = w & 7;
  if (c >= 4) return;
  int s = w >> 3;                  // 0..7  j-slice
  int d = c >> 1, g = c & 1;
  int tid = threadIdx.x;
  int wv = tid >> 6, l = tid & 63;
  int lr = l & 15, lq = l >> 4;
  int jglob = s * 64 + wv * 16 + lr;   // lane's output column
  int b0 = g * 16;

  __shared__ __align__(16) u16 wHiS[64 * 512];             // 64KB
  __shared__ __align__(16) u16 wLoS[64 * 512];             // 64KB
  __shared__ __align__(16) unsigned char hHiS[16 * 1024];  // 16KB
  __shared__ __align__(16) unsigned char hLoS[16 * 1024];  // 16KB

  // stage Whh j-slice into LDS, split hi/lo, chunk-swizzled (chunk ^= row&7)
  {
    const float* Wsrc = Whh + ((size_t)d * H_ + s * 64) * H_;
    for (int i = tid; i < 64 * 512; i += 256) {
      int nloc = i >> 9, k = i & 511;
      float v = Wsrc[(size_t)nloc * H_ + k];
      u16 hv = f2bf(v), lv = f2bf(v - bf2f(hv));
      u32 byteo = nloc * 1024 + ((((u32)(k >> 3)) ^ (u32)(nloc & 7)) << 4) + (k & 7) * 2;
      *(u16*)((char*)wHiS + byteo) = hv;
      *(u16*)((char*)wLoS + byteo) = lv;
    }
  }
  // h_{-1} = 0
  {
    f32x4 z = {0.f, 0.f, 0.f, 0.f};
    for (int i = tid; i < 1024; i += 256) {
      *(f32x4*)(hHiS + i * 16) = z;
      *(f32x4*)(hLoS + i * 16) = z;
    }
  }
  __syncthreads();

  // B-fragments: B[k][n]=Whh[n][k]; lane: n=lr (col jglob), k=kk*32+lq*8+e.
  // Pin in VGPRs (asm) so the compiler cannot rematerialize per step.
  bf16x8 Bhi[16], Blo[16];
  {
    int nloc = wv * 16 + lr;
#pragma unroll
    for (int kk = 0; kk < 16; kk++) {
      u32 off = nloc * 1024 + ((u32)((kk * 4 + lq) ^ (nloc & 7)) << 4);
      Bhi[kk] = *(const bf16x8*)((const char*)wHiS + off);
      Blo[kk] = *(const bf16x8*)((const char*)wLoS + off);
    }
  }
#pragma unroll
  for (int kk = 0; kk < 16; kk++)
    asm volatile("" : "+v"(Bhi[kk]), "+v"(Blo[kk]));

  float bias = 0.f;
  if (layer == 0) bias = bih[d * H_ + jglob] + bhh[d * H_ + jglob];

  int* flagp = flags + ((layer * 2 + d) * 2 + g) * T_;
  u32* hxg = hx + (size_t)(d * 2 + g) * 16384;

  auto loadPre = [&](int tau, float* dst) {
#pragma unroll
    for (int r = 0; r < 4; r++) {
      int b = b0 + lq * 4 + r;
      if (layer == 0) {
        int xv = xIdx[b * T_ + tau];
        dst[r] = WT0[((size_t)d * V_ + xv) * H_ + jglob];
      } else {
        dst[r] = preBuf[(((size_t)d * B_ + b) * T_ + tau) * H_ + jglob];
      }
    }
  };

  float preC[4];
  loadPre((d == 0) ? 0 : T_ - 1, preC);

  for (int t = 0; t < T_; t++) {
    int tau = (d == 0) ? t : (T_ - 1 - t);

    float preN[4];
    if (t < T_ - 1) {                      // prefetch next pre (L2 stays warm now)
      int tauN = (d == 0) ? (t + 1) : (T_ - 2 - t);
      loadPre(tauN, preN);
    }

    // acc = h_prev @ Whh_slice^T via 3 split products (hh + hl + lh)
    f32x4 acc0 = {0.f, 0.f, 0.f, 0.f}, acc1 = acc0, acc2 = acc0;
#pragma unroll
    for (int kk = 0; kk < 16; kk++) {
      u32 choff = ((u32)((kk * 4 + lq) ^ (lr & 7))) << 4;
      bf16x8 ah = *(const bf16x8*)(hHiS + lr * 1024 + choff);
      bf16x8 al = *(const bf16x8*)(hLoS + lr * 1024 + choff);
      acc0 = mfma16(ah, Bhi[kk], acc0);
      acc1 = mfma16(ah, Blo[kk], acc1);
      acc2 = mfma16(al, Bhi[kk], acc2);
    }

    // epilogue: tanh, split, publish. D: col=lr (j), row=lq*4+r (batch)
    int par = t & 1;
    u32* hxp = hxg + (par ? 8192 : 0);
#pragma unroll
    for (int r = 0; r < 4; r++) {
      float v = acc0[r] + acc1[r] + acc2[r] + preC[r] + bias;
      v = tanh_fast(v);
      u16 hv = f2bf(v), lv = f2bf(v - bf2f(hv));
      int bl = lq * 4 + r;
      size_t addr = (((size_t)(b0 + bl)) * T_ + tau) * HC_ + d * H_ + jglob;
      hHiOut[addr] = hv;                   // cached stores (read by later GEMM)
      hLoOut[addr] = lv;
      if (t < T_ - 1)
        __hip_atomic_store(hxp + bl * 512 + jglob, ((u32)hv << 16) | (u32)lv,
                           __ATOMIC_RELAXED, __HIP_MEMORY_SCOPE_AGENT);
    }

    if (t < T_ - 1) {
      __syncthreads();                     // drains vmcnt(0): hx stores at MALL
      if (tid == 0) {
        __hip_atomic_fetch_add(flagp + t, 1, __ATOMIC_RELAXED, __HIP_MEMORY_SCOPE_AGENT);
        while (__hip_atomic_load(flagp + t, __ATOMIC_RELAXED, __HIP_MEMORY_SCOPE_AGENT) < 8)
          __builtin_amdgcn_s_sleep(2);
      }
      __syncthreads();                     // all waves see completed exchange

      // restage h(tau) from MALL: 32 packed words/thread, unpack to planes
      {
        int row = tid >> 4;
        int j0 = (tid & 15) * 32;
        const u32* src = hxp + row * 512 + j0;
        u32 wbuf[32];
#pragma unroll
        for (int i2 = 0; i2 < 32; i2++)
          wbuf[i2] = __hip_atomic_load(src + i2, __ATOMIC_RELAXED, __HIP_MEMORY_SCOPE_AGENT);
#pragma unroll
        for (int cch = 0; cch < 4; cch++) {
          u32x4 hiw, low;
#pragma unroll
          for (int e = 0; e < 4; e++) {
            u32 a = wbuf[cch * 8 + e * 2], b2 = wbuf[cch * 8 + e * 2 + 1];
            hiw[e] = (a >> 16) | (b2 & 0xffff0000u);
            low[e] = (a & 0xffffu) | (b2 << 16);
          }
          u32 chunk = (u32)(j0 >> 3) + cch;
          u32 byteo = row * 1024 + ((chunk ^ (u32)(row & 7)) << 4);
          *(u32x4*)(hHiS + byteo) = hiw;
          *(u32x4*)(hLoS + byteo) = low;
        }
      }
      __syncthreads();                     // staging visible to next step's reads
#pragma unroll
      for (int r = 0; r < 4; r++) preC[r] = preN[r];
    }
  }
}

// ---------------------------------------------------------------------------
// GEMM  C[M=65536][N=1024] = A[M][K] * B[N][K]^T (+bias1[n] +bias2[n])
// (unchanged from passing v2; <1ms combined, not the bottleneck)
// ---------------------------------------------------------------------------
__global__ __launch_bounds__(256, 2) void gemm_split3(
    const u16* __restrict__ Ahi, const u16* __restrict__ Alo,
    const u16* __restrict__ Bhi, const u16* __restrict__ Blo,
    float* __restrict__ Cout,
    const float* __restrict__ bias1, const float* __restrict__ bias2,
    int Kdim, int outMode) {
  __shared__ __align__(16) u16 AsH[128 * 64], AsL[128 * 64];
  __shared__ __align__(16) u16 BsH[128 * 64], BsL[128 * 64];
  int tid = threadIdx.x;
  int wv = tid >> 6, l = tid & 63, lr = l & 15, lq = l >> 4;
  int wr = wv >> 1, wc = wv & 1;
  size_t row0 = (size_t)blockIdx.y * 128;
  int col0 = blockIdx.x * 128;

  f32x4 zero = {0.f, 0.f, 0.f, 0.f};
  f32x4 acc[4][4];
#pragma unroll
  for (int i = 0; i < 4; i++)
#pragma unroll
    for (int j = 0; j < 4; j++) acc[i][j] = zero;

  int nk = Kdim >> 6;
  for (int ks = 0; ks < nk; ks++) {
    __syncthreads();
#pragma unroll
    for (int it = 0; it < 4; it++) {       // stage 4 x 16KB, swizzled dest
      int ci = it * 256 + tid;
      int row = ci >> 3;
      int cg = ci & 7;
      u32 dsb = row * 128 + ((cg ^ (row & 7)) << 4);
      size_t ga = (row0 + row) * (size_t)Kdim + ks * 64 + cg * 8;
      size_t gb = ((size_t)(col0 + row)) * (size_t)Kdim + ks * 64 + cg * 8;
      *(f32x4*)((char*)AsH + dsb) = *(const f32x4*)(Ahi + ga);
      *(f32x4*)((char*)AsL + dsb) = *(const f32x4*)(Alo + ga);
      *(f32x4*)((char*)BsH + dsb) = *(const f32x4*)(Bhi + gb);
      *(f32x4*)((char*)BsL + dsb) = *(const f32x4*)(Blo + gb);
    }
    __syncthreads();
#pragma unroll
    for (int kk = 0; kk < 2; kk++) {
      bf16x8 aH[4], aL[4], bH[4], bL[4];
#pragma unroll
      for (int mt = 0; mt < 4; mt++) {
        int row = wr * 64 + mt * 16 + lr;
        u32 off = row * 128 + (((kk * 4 + lq) ^ (row & 7)) << 4);
        aH[mt] = *(const bf16x8*)((const char*)AsH + off);
        aL[mt] = *(const bf16x8*)((const char*)AsL + off);
      }
#pragma unroll
      for (int nt = 0; nt < 4; nt++) {
        int row = wc * 64 + nt * 16 + lr;
        u32 off = row * 128 + (((kk * 4 + lq) ^ (row & 7)) << 4);
        bH[nt] = *(const bf16x8*)((const char*)BsH + off);
        bL[nt] = *(const bf16x8*)((const char*)BsL + off);
      }
#pragma unroll
      for (int mt = 0; mt < 4; mt++)
#pragma unroll
        for (int nt = 0; nt < 4; nt++) {
          acc[mt][nt] = mfma16(aH[mt], bH[nt], acc[mt][nt]);
          acc[mt][nt] = mfma16(aH[mt], bL[nt], acc[mt][nt]);
          acc[mt][nt] = mfma16(aL[mt], bH[nt], acc[mt][nt]);
        }
    }
  }
#pragma unroll
  for (int mt = 0; mt < 4; mt++)
#pragma unroll
    for (int nt = 0; nt < 4; nt++)
#pragma unroll
      for (int r = 0; r < 4; r++) {
        size_t row = row0 + wr * 64 + mt * 16 + lq * 4 + r;
        int n = col0 + wc * 64 + nt * 16 + lr;
        float v = acc[mt][nt][r];
        if (bias1) v += bias1[n];
        if (bias2) v += bias2[n];
        size_t oaddr = outMode ? ((size_t)(n >> 9) * ((size_t)65536 * 512) + row * 512 + (n & 511))
                               : (row * 1024 + n);
        Cout[oaddr] = v;
      }
}

// ---------------------------------------------------------------------------
extern "C" void kernel_launch(void* const* d_in, const int* in_sizes, int n_in,
                              void* d_out, int out_size, void* d_ws, size_t ws_size,
                              hipStream_t stream) {
  (void)in_sizes; (void)n_in; (void)out_size; (void)ws_size;
  const int*   x    = (const int*)d_in[0];
  const float* Wih0 = (const float*)d_in[1];
  const float* Whh0 = (const float*)d_in[2];
  const float* bih0 = (const float*)d_in[3];
  const float* bhh0 = (const float*)d_in[4];
  const float* Wih1 = (const float*)d_in[5];
  const float* Whh1 = (const float*)d_in[6];
  const float* bih1 = (const float*)d_in[7];
  const float* bhh1 = (const float*)d_in[8];
  const float* fcW  = (const float*)d_in[9];
  const float* fcb  = (const float*)d_in[10];
  float* out = (float*)d_out;

  // workspace layout (16B-aligned carve): ~553 MB
  char* w = (char*)d_ws;
  float* WT0   = (float*)w;  w += (size_t)2 * V_ * H_ * 4;        // 32 MB
  u16* Wih1Hi  = (u16*)w;    w += (size_t)HC_ * HC_ * 2;          // 2 MB
  u16* Wih1Lo  = (u16*)w;    w += (size_t)HC_ * HC_ * 2;
  u16* fcWHi   = (u16*)w;    w += (size_t)HC_ * HC_ * 2;
  u16* fcWLo   = (u16*)w;    w += (size_t)HC_ * HC_ * 2;
  int* flags   = (int*)w;    w += (size_t)2 * 2 * 2 * T_ * 4;     // 64 KB
  u32* hx      = (u32*)w;    w += (size_t)4 * 2 * 16 * 512 * 4;   // 256 KB
  u16* hHi     = (u16*)w;    w += (size_t)B_ * T_ * HC_ * 2;      // 128 MB
  u16* hLo     = (u16*)w;    w += (size_t)B_ * T_ * HC_ * 2;      // 128 MB
  float* pre1  = (float*)w;  w += (size_t)2 * B_ * T_ * H_ * 4;   // 256 MB

  hipMemsetAsync(flags, 0, (size_t)2 * 2 * 2 * T_ * 4, stream);

  transpose_wih0<<<dim3(V_ / 32, H_ / 32, 2), dim3(32, 8), 0, stream>>>(Wih0, WT0);
  split_hilo<<<(HC_ * HC_) / 256, 256, 0, stream>>>(Wih1, Wih1Hi, Wih1Lo, HC_ * HC_);
  split_hilo<<<(HC_ * HC_) / 256, 256, 0, stream>>>(fcW, fcWHi, fcWLo, HC_ * HC_);

  // layer 0 scan (writes hHi/hLo)
  rnn_scan<<<64, 256, 0, stream>>>(Whh0, WT0, x, bih0, bhh0, nullptr,
                                   hHi, hLo, hx, flags, 0);
  // layer 1 pre = h0cat @ Wih1^T + bih1 + bhh1  -> pre1 [2][B*T][512]
  gemm_split3<<<dim3(8, 512), 256, 0, stream>>>(hHi, hLo, Wih1Hi, Wih1Lo, pre1,
                                                bih1, bhh1, HC_, 1);
  // layer 1 scan (reads pre1, overwrites hHi/hLo with h1)
  rnn_scan<<<64, 256, 0, stream>>>(Whh1, nullptr, nullptr, nullptr, nullptr,
                                   pre1, hHi, hLo, hx, flags, 1);
  // FC: out = h1cat @ fcW^T + fcb
  gemm_split3<<<dim3(8, 512), 256, 0, stream>>>(hHi, hLo, fcWHi, fcWLo, out,
                                                fcb, nullptr, HC_, 0);
}